// Round 2
// 231.999 us; speedup vs baseline: 1.0102x; 1.0102x over previous
//
#include <hip/hip_runtime.h>
#include <stdint.h>

// WeightsDropout: per row of 4096 f32 (uniform in (1e-4,1)), drop the 2048
// smallest (stable tie-break: smaller index dropped first), softmax survivors.
//
// R5b: 1 row per 256-thread block, __launch_bounds__(256,8) -> target 64 VGPR
// class, 8 blocks/CU resident (was 4) so load/compute/store phases of
// different blocks interleave (kernel was latency-bound: VALU 33%, HBM 29%,
// occupancy 48.5%). Histogram folded into the pre-barrier region; 256-bucket
// scan + crossing-bucket select done by wave 0 alone (int4 LDS read + shuffle
// scan) -> 6 barriers/row. Output stored non-temporal via native ext_vector
// float4 (__builtin_nontemporal_store rejects HIP_vector_type).
// Selection: uniform values -> k-th order statistic in [0.45,0.55) whp;
// fine 256-bucket histogram over that band (~410 elems/row), exact
// lex-(bits,idx) rank inside the crossing bucket. Block-uniform exact
// bisection fallback guarantees correctness for any input.
constexpr int N     = 4096;
constexpr int KSEL  = 2048;          // int(N * 0.5)
constexpr int BLOCK = 256;
constexpr int NW    = BLOCK / 64;    // 4 waves
constexpr int EPT   = N / BLOCK;     // 16 elements/thread
constexpr int NB    = 256;           // fine buckets over the band
constexpr int CAP   = 128;           // candidate capacity (E[#]=1.6)
constexpr float P1  = 0.45f;
constexpr float P2  = 0.55f;
constexpr float BSCALE = 2560.0f;    // NB / (P2 - P1)

typedef float vfloat4 __attribute__((ext_vector_type(4)));

__global__ __launch_bounds__(BLOCK, 8)
void wdrop_kernel(const float* __restrict__ w, float* __restrict__ out) {
    const int t = threadIdx.x, wid = t >> 6, lane = t & 63;
    const uint64_t row = blockIdx.x;

    __shared__ alignas(16) int hist[NB];
    __shared__ uint32_t redu[NW];
    __shared__ int      redi[NW];
    __shared__ float    redf[NW];
    __shared__ int      selb, selc, cn;
    __shared__ uint32_t cb[CAP];
    __shared__ int      ci[CAP];
    __shared__ uint32_t thrT, thrI;

    // ---- issue all 4 float4 loads up front, zero LDS while in flight
    uint32_t v[EPT];
    {
        const uint4* wf = (const uint4*)(w + row * N);
        uint4 u[EPT / 4];
#pragma unroll
        for (int j = 0; j < EPT / 4; ++j) u[j] = wf[j * BLOCK + t];
#pragma unroll
        for (int j = 0; j < EPT / 4; ++j) {
            v[j*4+0] = u[j].x; v[j*4+1] = u[j].y;
            v[j*4+2] = u[j].z; v[j*4+3] = u[j].w;
        }
    }
    hist[t] = 0;
    if (t == 0) cn = 0;

    // ---- per-thread max + band counts (clo = #(<P1), chi = #(<P2))
    uint32_t mx = v[0];
    int clo = 0, chi = 0;
#pragma unroll
    for (int e = 0; e < EPT; ++e) {
        mx = max(mx, v[e]);
        const float f = __uint_as_float(v[e]);
        clo += (f < P1); chi += (f < P2);
    }
    int pk = (clo << 16) | chi;      // fields stay < 4096: no carry
#pragma unroll
    for (int off = 32; off > 0; off >>= 1) {
        mx = max(mx, (uint32_t)__shfl_xor((int)mx, off, 64));
        pk += __shfl_xor(pk, off, 64);
    }
    if (lane == 0) { redu[wid] = mx; redi[wid] = pk; }
    __syncthreads();                                          // A (hist zero + wave reduces)

    // ---- band histogram, unconditional (~10% of elems); overlap with
    //      reading the block-level reduction everyone needs anyway
#pragma unroll
    for (int e = 0; e < EPT; ++e) {
        const float f = __uint_as_float(v[e]);
        if (f >= P1 && f < P2) {
            const int bk = min((int)((f - P1) * BSCALE), NB - 1);
            atomicAdd(&hist[bk], 1);
        }
    }
    uint32_t mxb = redu[0]; int pkt = redi[0];
#pragma unroll
    for (int i = 1; i < NW; ++i) { mxb = max(mxb, redu[i]); pkt += redi[i]; }
    const int cloB = pkt >> 16, chiB = pkt & 0xFFFF;
    const bool fastp = (cloB < KSEL) && (chiB >= KSEL);  // k-th value in [P1,P2)
    const int jrank = KSEL - cloB;                       // rank needed within band
    __syncthreads();                                          // B (hist complete)

    // ---- wave-0-only scan of 256 buckets + crossing-bucket select
    if (wid == 0) {
        const int4 hh = ((const int4*)hist)[lane];           // 4 buckets/lane
        const int a0 = hh.x, a1 = a0 + hh.y, a2 = a1 + hh.z, a3 = a2 + hh.w;
        int sc = a3;
#pragma unroll
        for (int off = 1; off < 64; off <<= 1) {
            const int u = __shfl_up(sc, off, 64);
            if (lane >= off) sc += u;
        }
        const int base = sc - a3;        // exclusive prefix of this lane's 4
        if (fastp) {
            const int inc[4] = {base + a0, base + a1, base + a2, base + a3};
            const int exc[4] = {base, base + a0, base + a1, base + a2};
#pragma unroll
            for (int i = 0; i < 4; ++i)
                if (exc[i] < jrank && jrank <= inc[i]) { selb = lane * 4 + i; selc = exc[i]; }
        }
    }
    __syncthreads();                                          // C (selb/selc)

    // ---- gather candidates in crossing bucket
    if (fastp) {
        const int bs = selb;
#pragma unroll
        for (int e = 0; e < EPT; ++e) {
            const float f = __uint_as_float(v[e]);
            if (f >= P1 && f < P2 && min((int)((f - P1) * BSCALE), NB - 1) == bs) {
                const int slot = atomicAdd(&cn, 1);
                if (slot < CAP) {
                    cb[slot] = v[e];
                    ci[slot] = ((e >> 2) * BLOCK + t) * 4 + (e & 3);
                }
            }
        }
    }
    __syncthreads();                                          // D (candidates)

    // ---- exact lex rank among candidates -> (T, thrIdx) = k-th smallest pair
    const bool ok = fastp && (cn <= CAP);
    if (ok && t < cn) {
        const uint32_t myb = cb[t]; const int myi = ci[t];
        const int cc = cn;
        int rank = 0;
        for (int q = 0; q < cc; ++q)
            rank += (cb[q] < myb) || (cb[q] == myb && ci[q] < myi);
        if (rank == jrank - selc - 1) { thrT = myb; thrI = (uint32_t)myi; }
    }

    // ---- exact fallback (block-uniform; never taken for uniform data)
    if (!ok) {
        uint32_t blo = 0u, bhi = 0x7f7fffffu;
        while (blo < bhi) {
            const uint32_t mid = blo + ((bhi - blo) >> 1);
            int c = 0;
#pragma unroll
            for (int e = 0; e < EPT; ++e) c += __popcll(__ballot(v[e] <= mid));
            __syncthreads();
            if (lane == 0) redi[wid] = c;
            __syncthreads();
            int tot = 0;
#pragma unroll
            for (int i = 0; i < NW; ++i) tot += redi[i];
            if (tot >= KSEL) bhi = mid; else blo = mid + 1;
        }
        const uint32_t T = blo;
        int c = 0;
#pragma unroll
        for (int e = 0; e < EPT; ++e) c += __popcll(__ballot(v[e] < T));
        __syncthreads();
        if (lane == 0) redi[wid] = c;
        __syncthreads();
        int clt = 0;
#pragma unroll
        for (int i = 0; i < NW; ++i) clt += redi[i];
        const int need = KSEL - clt;
        int ilo = 0, ihi = N - 1;
        while (ilo < ihi) {
            const int imid = (ilo + ihi) >> 1;
            int cc2 = 0;
#pragma unroll
            for (int e = 0; e < EPT; ++e) {
                const int idx = ((e >> 2) * BLOCK + t) * 4 + (e & 3);
                cc2 += __popcll(__ballot(v[e] == T && idx <= imid));
            }
            __syncthreads();
            if (lane == 0) redi[wid] = cc2;
            __syncthreads();
            int tot = 0;
#pragma unroll
            for (int i = 0; i < NW; ++i) tot += redi[i];
            if (tot >= need) ihi = imid; else ilo = imid + 1;
        }
        if (t == 0) { thrT = T; thrI = (uint32_t)ilo; }
    }
    __syncthreads();                                          // E (threshold)

    // ---- keep + exp + block sum, then scale + NT store
    const uint32_t T = thrT; const int ti = (int)thrI;
    const float m = __uint_as_float(mxb);
    float acc = 0.0f;
#pragma unroll
    for (int e = 0; e < EPT; ++e) {
        const int idx = ((e >> 2) * BLOCK + t) * 4 + (e & 3);
        const bool keep = (v[e] > T) || (v[e] == T && idx > ti);
        const float ev = keep ? __expf(__uint_as_float(v[e]) - m) : 0.0f;
        v[e] = __float_as_uint(ev);
        acc += ev;
    }
#pragma unroll
    for (int off = 32; off > 0; off >>= 1) acc += __shfl_xor(acc, off, 64);
    if (lane == 0) redf[wid] = acc;
    __syncthreads();                                          // F (sum)
    float s = redf[0];
#pragma unroll
    for (int i = 1; i < NW; ++i) s += redf[i];
    const float inv = 1.0f / s;

    vfloat4* of = (vfloat4*)(out + row * N);
#pragma unroll
    for (int j = 0; j < EPT / 4; ++j) {
        vfloat4 o;
        o.x = __uint_as_float(v[j*4+0]) * inv;
        o.y = __uint_as_float(v[j*4+1]) * inv;
        o.z = __uint_as_float(v[j*4+2]) * inv;
        o.w = __uint_as_float(v[j*4+3]) * inv;
        __builtin_nontemporal_store(o, &of[j * BLOCK + t]);
    }
}

extern "C" void kernel_launch(void* const* d_in, const int* in_sizes, int n_in,
                              void* d_out, int out_size, void* d_ws, size_t ws_size,
                              hipStream_t stream) {
    const float* w = (const float*)d_in[0];
    float* out = (float*)d_out;
    const int rows = in_sizes[0] / N;            // 8192
    wdrop_kernel<<<rows, BLOCK, 0, stream>>>(w, out);
}